// Round 1
// baseline (584.439 us; speedup 1.0000x reference)
//
#include <hip/hip_runtime.h>
#include <math.h>

#define CIN 256
#define COUT 64
#define KN 1024
#define PN 80000
#define SIMT 0.9f

// ---------------------------------------------------------------------------
// Kernel A: mw = feat^T @ W^T + b  (1024x64), then a = row-normalize(mw).
// One wave (64 lanes) per k-row; lane = o. W row cached in L1.
// ---------------------------------------------------------------------------
__global__ __launch_bounds__(256) void k_mw(const float* __restrict__ idx_feat,
                                            const float* __restrict__ W,
                                            const float* __restrict__ b,
                                            float* __restrict__ mw,
                                            float* __restrict__ a) {
    int t = threadIdx.x;
    int id = blockIdx.x * 256 + t;
    int k = id >> 6;      // wave-uniform (64 threads per k)
    int o = id & 63;
    const float4* W4 = (const float4*)W;
    float acc = 0.f;
    #pragma unroll 4
    for (int c4 = 0; c4 < 64; ++c4) {
        float4 wv = W4[o * 64 + c4];
        int c = c4 * 4;
        acc += idx_feat[(c + 0) * KN + k] * wv.x
             + idx_feat[(c + 1) * KN + k] * wv.y
             + idx_feat[(c + 2) * KN + k] * wv.z
             + idx_feat[(c + 3) * KN + k] * wv.w;
    }
    float v = acc + b[o];
    mw[k * COUT + o] = v;
    // norm over the 64 lanes of this wave (one k-row per wave)
    float ss = v * v;
    #pragma unroll
    for (int m = 1; m < 64; m <<= 1) ss += __shfl_xor(ss, m, 64);
    float nrm = sqrtf(ss);
    a[k * COUT + o] = v / fmaxf(nrm, 1e-8f);
}

// ---------------------------------------------------------------------------
// Kernel B: per column j: sim[i,j], label = triu & (sim>=0.9) & cate-match,
// column-wise prefix count < 2 (cum), keep[j] = cum[j,j],
// packed bitmask of (label & cum) per column -> mask[j*32 + w].
// One block per column, thread t owns i = 4t..4t+3 (contiguous for the scan).
// ---------------------------------------------------------------------------
__global__ __launch_bounds__(256) void k_label(const float* __restrict__ a,
                                               const int* __restrict__ cate,
                                               unsigned int* __restrict__ mask,
                                               unsigned int* __restrict__ keep) {
    int j = blockIdx.x;
    int t = threadIdx.x;
    __shared__ __align__(16) float ajs[64];
    __shared__ int cnts[256];
    __shared__ unsigned int mws[32];
    if (t < 64) ajs[t] = a[j * 64 + t];
    if (t < 32) mws[t] = 0u;
    __syncthreads();
    int cj = cate[j];
    const float4* a4  = (const float4*)a;
    const float4* aj4 = (const float4*)ajs;
    bool lab[4];
    int cnt = 0;
    #pragma unroll
    for (int q = 0; q < 4; ++q) {
        int i = t * 4 + q;
        float s = 0.f;
        #pragma unroll
        for (int c4 = 0; c4 < 16; ++c4) {
            float4 av = a4[i * 16 + c4];
            float4 jv = aj4[c4];
            s += av.x * jv.x + av.y * jv.y + av.z * jv.z + av.w * jv.w;
        }
        lab[q] = (i <= j) && (s >= SIMT) && (cate[i] == cj);
        cnt += lab[q] ? 1 : 0;
    }
    cnts[t] = cnt;
    __syncthreads();
    // inclusive Hillis-Steele scan over the 256 per-thread counts
    for (int off = 1; off < 256; off <<= 1) {
        int v = cnts[t];
        int add = (t >= off) ? cnts[t - off] : 0;
        __syncthreads();
        cnts[t] = v + add;
        __syncthreads();
    }
    int run = cnts[t] - cnt;  // exclusive prefix for i = 4t
    #pragma unroll
    for (int q = 0; q < 4; ++q) {
        int i = t * 4 + q;
        run += lab[q] ? 1 : 0;           // inclusive count at row i
        bool cumf = run < 2;
        if (lab[q] && cumf) atomicOr(&mws[i >> 5], 1u << (i & 31));
        if (i == j) keep[j] = cumf ? 1u : 0u;
    }
    __syncthreads();
    if (t < 32) mask[j * 32 + t] = mws[t];
}

// ---------------------------------------------------------------------------
// Kernel C: merged[i,c] = keep[i] * sum_j lm[i,j]*mw[j,c] / max(cnt,1).
// One block per row i; 4 groups of 64 lanes (lane = c) walk j ranges.
// Stores TRANSPOSED: mergedT[c*KN + i] (for wave-uniform scalar loads in D).
// ---------------------------------------------------------------------------
__global__ __launch_bounds__(256) void k_merge(const float* __restrict__ mw,
                                               const unsigned int* __restrict__ mask,
                                               const unsigned int* __restrict__ keep,
                                               float* __restrict__ mergedT) {
    int i = blockIdx.x;
    int t = threadIdx.x;
    int c = t & 63, g = t >> 6;
    int wi = i >> 5;
    unsigned int bi = 1u << (i & 31);
    float acc = 0.f;
    int cnt = 0;
    for (int jj = 0; jj < 256; ++jj) {
        int j = g * 256 + jj;
        unsigned int wv = mask[j * 32 + wi];   // wave-uniform
        if (wv & bi) { acc += mw[j * 64 + c]; cnt++; }
    }
    __shared__ float sa[4][64];
    __shared__ int sc[4];
    sa[g][c] = acc;
    if (c == 0) sc[g] = cnt;
    __syncthreads();
    if (g == 0) {
        float tot = sa[0][c] + sa[1][c] + sa[2][c] + sa[3][c];
        int ct = sc[0] + sc[1] + sc[2] + sc[3];
        float mv = keep[i] ? tot / (float)max(ct, 1) : 0.f;
        mergedT[c * KN + i] = mv;
    }
}

// ---------------------------------------------------------------------------
// Kernel D: inst[k,p] = sum_c merged[k,c] * x[c,p].  THE hot kernel.
// Block = 256 p-cols x 256 k-rows. x tile (64c x 256p fp32 = 64 KB) in LDS.
// Thread: 4 consecutive p (float4) x 16 k accumulators -> LDS traffic /16.
// mergedT[c*KN + k0 + kk] is wave-uniform -> scalar loads.
// ---------------------------------------------------------------------------
__global__ __launch_bounds__(256) void k_inst(const float* __restrict__ x,
                                              const float* __restrict__ mergedT,
                                              float* __restrict__ out) {
    __shared__ __align__(16) float xt[64 * 256];
    int t = threadIdx.x;
    int pbase = blockIdx.x * 256;
    int kchunk = blockIdx.y;         // 4 chunks of 256 k
    // stage x tile: 4096 float4 slots, 16 per thread, coalesced rows
    #pragma unroll
    for (int it = 0; it < 16; ++it) {
        int idx = it * 256 + t;
        int c = idx >> 6;
        int p4 = (idx & 63) << 2;
        float4 v = make_float4(0.f, 0.f, 0.f, 0.f);
        int p = pbase + p4;
        if (p < PN) v = *(const float4*)(x + c * PN + p);
        *(float4*)(xt + c * 256 + p4) = v;
    }
    __syncthreads();
    int pq = t & 63;                 // p-lane within wave
    int kg = t >> 6;                 // wave id -> 16-k slice (wave-uniform)
    int p = pbase + pq * 4;
    bool valid = p < PN;
    for (int sub = 0; sub < 4; ++sub) {
        int k0 = kchunk * 256 + sub * 64 + kg * 16;
        float4 acc[16];
        #pragma unroll
        for (int kk = 0; kk < 16; ++kk) acc[kk] = make_float4(0.f, 0.f, 0.f, 0.f);
        #pragma unroll 4
        for (int c = 0; c < 64; ++c) {
            float4 xv = *(const float4*)(xt + c * 256 + pq * 4);
            const float* mrow = mergedT + c * KN + k0;   // wave-uniform base
            #pragma unroll
            for (int kk = 0; kk < 16; ++kk) {
                float m = mrow[kk];
                acc[kk].x += m * xv.x;
                acc[kk].y += m * xv.y;
                acc[kk].z += m * xv.z;
                acc[kk].w += m * xv.w;
            }
        }
        if (valid) {
            #pragma unroll
            for (int kk = 0; kk < 16; ++kk) {
                *(float4*)(out + (long)(k0 + kk) * PN + p) = acc[kk];
            }
        }
    }
}

// ---------------------------------------------------------------------------
// Kernel E: tail outputs: keep (as 0/1 float), pred_cate (as float), score.
// ---------------------------------------------------------------------------
__global__ void k_tail(const int* __restrict__ cate,
                       const float* __restrict__ score,
                       const unsigned int* __restrict__ keep,
                       float* __restrict__ out) {
    int t = blockIdx.x * 256 + threadIdx.x;
    if (t < KN) {
        long base = (long)KN * PN;
        out[base + t]            = keep[t] ? 1.f : 0.f;
        out[base + KN + t]       = (float)cate[t];
        out[base + 2 * KN + t]   = score[t];
    }
}

extern "C" void kernel_launch(void* const* d_in, const int* in_sizes, int n_in,
                              void* d_out, int out_size, void* d_ws, size_t ws_size,
                              hipStream_t stream) {
    // setup_inputs order: x, idx_feat, pred_cate, pred_score, W, b, n, h, w
    const float* x        = (const float*)d_in[0];   // (64, 80000)
    const float* idx_feat = (const float*)d_in[1];   // (256, 1024)
    const int*   cate     = (const int*)d_in[2];     // (1024,)
    const float* score    = (const float*)d_in[3];   // (1024,)
    const float* W        = (const float*)d_in[4];   // (64, 256)
    const float* b        = (const float*)d_in[5];   // (64,)
    float* out = (float*)d_out;

    char* ws = (char*)d_ws;
    float* mw            = (float*)(ws + 0);         // 256 KB
    float* a             = (float*)(ws + 262144);    // 256 KB
    float* mergedT       = (float*)(ws + 524288);    // 256 KB
    unsigned int* mask   = (unsigned int*)(ws + 786432); // 128 KB
    unsigned int* keep   = (unsigned int*)(ws + 917504); // 4 KB
    // total ws need: 921600 bytes

    k_mw   <<<256,  256, 0, stream>>>(idx_feat, W, b, mw, a);
    k_label<<<KN,   256, 0, stream>>>(a, cate, mask, keep);
    k_merge<<<KN,   256, 0, stream>>>(mw, mask, keep, mergedT);
    dim3 gD((PN + 255) / 256, 4);
    k_inst <<<gD,   256, 0, stream>>>(x, mergedT, out);
    k_tail <<<4,    256, 0, stream>>>(cate, score, keep, out);
}

// Round 2
// 526.413 us; speedup vs baseline: 1.1102x; 1.1102x over previous
//
#include <hip/hip_runtime.h>
#include <math.h>

#define CIN 256
#define COUT 64
#define KN 1024
#define PN 80000
#define SIMT 0.9f

typedef __attribute__((ext_vector_type(8))) short  short8;   // 8 bf16 = 4 VGPRs
typedef __attribute__((ext_vector_type(4))) float  f32x4;    // MFMA acc

// fp32 -> bf16 round-to-nearest-even (bit pattern)
__device__ inline unsigned short f2bf(float f) {
    unsigned u = __float_as_uint(f);
    unsigned r = u + 0x7FFFu + ((u >> 16) & 1u);
    return (unsigned short)(r >> 16);
}

// ---------------------------------------------------------------------------
// Kernel A: mw = feat^T @ W^T + b  (1024x64), then a = row-normalize(mw).
// One wave (64 lanes) per k-row; lane = o.
// ---------------------------------------------------------------------------
__global__ __launch_bounds__(256) void k_mw(const float* __restrict__ idx_feat,
                                            const float* __restrict__ W,
                                            const float* __restrict__ b,
                                            float* __restrict__ mw,
                                            float* __restrict__ a) {
    int t = threadIdx.x;
    int id = blockIdx.x * 256 + t;
    int k = id >> 6;      // wave-uniform (64 threads per k)
    int o = id & 63;
    const float4* W4 = (const float4*)W;
    float acc = 0.f;
    #pragma unroll 4
    for (int c4 = 0; c4 < 64; ++c4) {
        float4 wv = W4[o * 64 + c4];
        int c = c4 * 4;
        acc += idx_feat[(c + 0) * KN + k] * wv.x
             + idx_feat[(c + 1) * KN + k] * wv.y
             + idx_feat[(c + 2) * KN + k] * wv.z
             + idx_feat[(c + 3) * KN + k] * wv.w;
    }
    float v = acc + b[o];
    mw[k * COUT + o] = v;
    float ss = v * v;
    #pragma unroll
    for (int m = 1; m < 64; m <<= 1) ss += __shfl_xor(ss, m, 64);
    float nrm = sqrtf(ss);
    a[k * COUT + o] = v / fmaxf(nrm, 1e-8f);
}

// ---------------------------------------------------------------------------
// Kernel B: per column j: sim[i,j], label = triu & (sim>=0.9) & cate-match,
// column-wise prefix count < 2 (cum), keep[j] = cum[j,j],
// packed bitmask of (label & cum) per column -> mask[j*32 + w].
// ---------------------------------------------------------------------------
__global__ __launch_bounds__(256) void k_label(const float* __restrict__ a,
                                               const int* __restrict__ cate,
                                               unsigned int* __restrict__ mask,
                                               unsigned int* __restrict__ keep) {
    int j = blockIdx.x;
    int t = threadIdx.x;
    __shared__ __align__(16) float ajs[64];
    __shared__ int cnts[256];
    __shared__ unsigned int mws[32];
    if (t < 64) ajs[t] = a[j * 64 + t];
    if (t < 32) mws[t] = 0u;
    __syncthreads();
    int cj = cate[j];
    const float4* a4  = (const float4*)a;
    const float4* aj4 = (const float4*)ajs;
    bool lab[4];
    int cnt = 0;
    #pragma unroll
    for (int q = 0; q < 4; ++q) {
        int i = t * 4 + q;
        float s = 0.f;
        #pragma unroll
        for (int c4 = 0; c4 < 16; ++c4) {
            float4 av = a4[i * 16 + c4];
            float4 jv = aj4[c4];
            s += av.x * jv.x + av.y * jv.y + av.z * jv.z + av.w * jv.w;
        }
        lab[q] = (i <= j) && (s >= SIMT) && (cate[i] == cj);
        cnt += lab[q] ? 1 : 0;
    }
    cnts[t] = cnt;
    __syncthreads();
    for (int off = 1; off < 256; off <<= 1) {
        int v = cnts[t];
        int add = (t >= off) ? cnts[t - off] : 0;
        __syncthreads();
        cnts[t] = v + add;
        __syncthreads();
    }
    int run = cnts[t] - cnt;
    #pragma unroll
    for (int q = 0; q < 4; ++q) {
        int i = t * 4 + q;
        run += lab[q] ? 1 : 0;
        bool cumf = run < 2;
        if (lab[q] && cumf) atomicOr(&mws[i >> 5], 1u << (i & 31));
        if (i == j) keep[j] = cumf ? 1u : 0u;
    }
    __syncthreads();
    if (t < 32) mask[j * 32 + t] = mws[t];
}

// ---------------------------------------------------------------------------
// Kernel C: merged[i,c] = keep[i] * sum_j lm[i,j]*mw[j,c] / max(cnt,1).
// One block per row i. Output: bf16 row-major mergedB[i*64+c] for MFMA A-frags.
// ---------------------------------------------------------------------------
__global__ __launch_bounds__(256) void k_merge(const float* __restrict__ mw,
                                               const unsigned int* __restrict__ mask,
                                               const unsigned int* __restrict__ keep,
                                               unsigned short* __restrict__ mergedB) {
    int i = blockIdx.x;
    int t = threadIdx.x;
    int c = t & 63, g = t >> 6;
    int wi = i >> 5;
    unsigned int bi = 1u << (i & 31);
    float acc = 0.f;
    int cnt = 0;
    for (int jj = 0; jj < 256; ++jj) {
        int j = g * 256 + jj;
        unsigned int wv = mask[j * 32 + wi];   // wave-uniform
        if (wv & bi) { acc += mw[j * 64 + c]; cnt++; }
    }
    __shared__ float sa[4][64];
    __shared__ int sc[4];
    sa[g][c] = acc;
    if (c == 0) sc[g] = cnt;
    __syncthreads();
    if (g == 0) {
        float tot = sa[0][c] + sa[1][c] + sa[2][c] + sa[3][c];
        int ct = sc[0] + sc[1] + sc[2] + sc[3];
        float mv = keep[i] ? tot / (float)max(ct, 1) : 0.f;
        mergedB[i * 64 + c] = f2bf(mv);
    }
}

// ---------------------------------------------------------------------------
// Kernel D: inst[k,p] = sum_c merged[k,c] * x[c,p] via bf16 MFMA 16x16x32.
// No LDS, no barriers. Wave owns 16 p-cols; B-frags (x cols, cvt fp32->bf16
// in-register) loaded ONCE per wave, reused over 32 m-tiles of 16 k-rows.
// A-frags stream from mergedB (128 KB, L1/L2-resident).
// Verified layouts (m89/m120): A[m=lane&15][k=quad*8+j]; B[n=lane&15][same k];
// C/D: col=lane&15, row=quad*4+reg.
// ---------------------------------------------------------------------------
__global__ __launch_bounds__(256) void k_inst(const float* __restrict__ x,
                                              const unsigned short* __restrict__ mergedB,
                                              float* __restrict__ out) {
    int t = threadIdx.x;
    int lane = t & 63;
    int wv = t >> 6;                        // wave id 0..3
    int n0 = blockIdx.x * 64 + wv * 16;     // p base for this wave
    int m0 = blockIdx.y * 512;              // k-row chunk base
    int nn = n0 + (lane & 15);              // this lane's p column
    int quad = lane >> 4;

    // B fragments: x[k][nn] for k = f*32 + quad*8 + j, converted to bf16
    short8 bfr[2];
    #pragma unroll
    for (int f = 0; f < 2; ++f) {
        #pragma unroll
        for (int j = 0; j < 8; ++j) {
            int k = f * 32 + quad * 8 + j;
            bfr[f][j] = (short)f2bf(x[k * PN + nn]);
        }
    }

    int arow_off = quad * 8;   // element offset of this lane's A k-octet
    #pragma unroll 4
    for (int mt = 0; mt < 32; ++mt) {
        int mrow = m0 + mt * 16 + (lane & 15);
        const unsigned short* ap = mergedB + mrow * 64 + arow_off;
        short8 a0 = *(const short8*)(ap);        // k 0..31 octet
        short8 a1 = *(const short8*)(ap + 32);   // k 32..63 octet
        f32x4 acc = {0.f, 0.f, 0.f, 0.f};
        acc = __builtin_amdgcn_mfma_f32_16x16x32_bf16(a0, bfr[0], acc, 0, 0, 0);
        acc = __builtin_amdgcn_mfma_f32_16x16x32_bf16(a1, bfr[1], acc, 0, 0, 0);
        int rbase = m0 + mt * 16 + quad * 4;
        #pragma unroll
        for (int r = 0; r < 4; ++r) {
            out[(rbase + r) * PN + nn] = acc[r];
        }
    }
}

// ---------------------------------------------------------------------------
// Kernel E: tail outputs: keep (0/1 float), pred_cate (float), score.
// ---------------------------------------------------------------------------
__global__ void k_tail(const int* __restrict__ cate,
                       const float* __restrict__ score,
                       const unsigned int* __restrict__ keep,
                       float* __restrict__ out) {
    int t = blockIdx.x * 256 + threadIdx.x;
    if (t < KN) {
        long base = (long)KN * PN;
        out[base + t]            = keep[t] ? 1.f : 0.f;
        out[base + KN + t]       = (float)cate[t];
        out[base + 2 * KN + t]   = score[t];
    }
}

extern "C" void kernel_launch(void* const* d_in, const int* in_sizes, int n_in,
                              void* d_out, int out_size, void* d_ws, size_t ws_size,
                              hipStream_t stream) {
    // setup_inputs order: x, idx_feat, pred_cate, pred_score, W, b, n, h, w
    const float* x        = (const float*)d_in[0];   // (64, 80000)
    const float* idx_feat = (const float*)d_in[1];   // (256, 1024)
    const int*   cate     = (const int*)d_in[2];     // (1024,)
    const float* score    = (const float*)d_in[3];   // (1024,)
    const float* W        = (const float*)d_in[4];   // (64, 256)
    const float* b        = (const float*)d_in[5];   // (64,)
    float* out = (float*)d_out;

    char* ws = (char*)d_ws;
    float*          mw      = (float*)(ws + 0);            // 256 KB
    float*          a       = (float*)(ws + 262144);       // 256 KB
    unsigned short* mergedB = (unsigned short*)(ws + 524288); // 128 KB (bf16)
    unsigned int*   mask    = (unsigned int*)(ws + 655360); // 128 KB
    unsigned int*   keep    = (unsigned int*)(ws + 786432); // 4 KB

    k_mw   <<<256,  256, 0, stream>>>(idx_feat, W, b, mw, a);
    k_label<<<KN,   256, 0, stream>>>(a, cate, mask, keep);
    k_merge<<<KN,   256, 0, stream>>>(mw, mask, keep, mergedB);
    dim3 gD(PN / 64, 2);   // 1250 x 2; each block: 64 p-cols x 512 k-rows
    k_inst <<<gD,   256, 0, stream>>>(x, mergedB, out);
    k_tail <<<4,    256, 0, stream>>>(cate, score, keep, out);
}